// Round 8
// baseline (922.536 us; speedup 1.0000x reference)
//
#include <hip/hip_runtime.h>

#define N_READ   200000
#define N_INTRON 50000
#define N_EDGES  2000000

#define NB    256                          // edge-segment blocks for hist/scatter
#define EPB   ((N_EDGES + NB - 1) / NB)    // 7813 edges per block
#define NBUK  782                          // buckets per direction (782*64>=50000, 782*256>=200000)
#define SH_I  6                            // intron bucket shift: 64 introns/bucket
#define SH_R  8                            // read bucket shift: 256 reads/bucket
#define NITEMS (NBUK * NB)                 // 200192 (divisible by 256)

typedef float f4 __attribute__((ext_vector_type(4)));
typedef float f2 __attribute__((ext_vector_type(2)));
typedef unsigned short u16x4 __attribute__((ext_vector_type(4)));

// bf16 helpers: storage-only bf16; all math in f32.
static __device__ __forceinline__ unsigned short f2bf(float x) {
  unsigned u = __builtin_bit_cast(unsigned, x);
  u = (u + 0x7fffu + ((u >> 16) & 1u)) >> 16;  // RTNE
  return (unsigned short)u;
}
static __device__ __forceinline__ void ga2(f2& a, unsigned u) {
  a[0] += __builtin_bit_cast(float, u << 16);
  a[1] += __builtin_bit_cast(float, u & 0xffff0000u);
}

// ---------------- bucket histograms (per-block LDS, no global atomics) ----------------
__global__ void kb_hist(const int* __restrict__ src, const int* __restrict__ dst,
                        int* __restrict__ histI, int* __restrict__ histR) {
  __shared__ int hI[1024], hR[1024];
  const int t = threadIdx.x, b = blockIdx.x;
  for (int k = t; k < 1024; k += 256) { hI[k] = 0; hR[k] = 0; }
  __syncthreads();
  const int s0 = b * EPB;
  const int s1 = (s0 + EPB < N_EDGES) ? s0 + EPB : N_EDGES;
  for (int i = s0 + t; i < s1; i += 256) {
    atomicAdd(&hI[dst[i] >> SH_I], 1);
    atomicAdd(&hR[src[i] >> SH_R], 1);
  }
  __syncthreads();
  for (int k = t; k < NBUK; k += 256) {
    histI[k * NB + b] = hI[k];
    histR[k * NB + b] = hR[k];
  }
}

// ---------------- exclusive scan (3 phases) ----------------
__global__ void k_scan1(const int* __restrict__ cnt, int* __restrict__ rp,
                        int* __restrict__ bsum, int n) {
  __shared__ int lds[256];
  int t = threadIdx.x;
  int i = blockIdx.x * 256 + t;
  int v = (i < n) ? cnt[i] : 0;
  lds[t] = v;
  __syncthreads();
  for (int off = 1; off < 256; off <<= 1) {
    int x = (t >= off) ? lds[t - off] : 0;
    __syncthreads();
    lds[t] += x;
    __syncthreads();
  }
  if (i < n) rp[i + 1] = lds[t];
  if (t == 255) bsum[blockIdx.x] = lds[255];
}

__global__ void k_scan2(int* __restrict__ bsum, int nb) {
  __shared__ int lds[1024];
  int t = threadIdx.x;
  int v = (t < nb) ? bsum[t] : 0;
  lds[t] = v;
  __syncthreads();
  for (int off = 1; off < 1024; off <<= 1) {
    int x = (t >= off) ? lds[t - off] : 0;
    __syncthreads();
    lds[t] += x;
    __syncthreads();
  }
  if (t < nb) bsum[t] = lds[t];
}

__global__ void k_scan3b(int* __restrict__ rp, const int* __restrict__ bsum, int n) {
  int i = blockIdx.x * 256 + threadIdx.x;
  if (i >= n) return;
  int off = (blockIdx.x == 0) ? 0 : bsum[blockIdx.x - 1];
  rp[i + 1] += off;
  if (i == 0) rp[0] = 0;
}

// ---------------- scatter edges into buckets (LDS cursors, packed u32 records) ----------------
__global__ void kb_scatter(const int* __restrict__ src, const int* __restrict__ dst,
                           const int* __restrict__ scanI, const int* __restrict__ scanR,
                           unsigned* __restrict__ bI, unsigned* __restrict__ bR) {
  __shared__ int cI[1024], cR[1024];
  const int t = threadIdx.x, b = blockIdx.x;
  for (int k = t; k < NBUK; k += 256) {
    cI[k] = scanI[k * NB + b];
    cR[k] = scanR[k * NB + b];
  }
  __syncthreads();
  const int s0 = b * EPB;
  const int s1 = (s0 + EPB < N_EDGES) ? s0 + EPB : N_EDGES;
  for (int i = s0 + t; i < s1; i += 256) {
    int s = src[i], d = dst[i];
    int slot = atomicAdd(&cI[d >> SH_I], 1);
    bI[slot] = ((unsigned)s << SH_I) | (unsigned)(d & 63);        // 18+6 = 24 bits
    int slot2 = atomicAdd(&cR[s >> SH_R], 1);
    bR[slot2] = ((unsigned)d << SH_R) | (unsigned)(s & 255);      // 16+8 = 24 bits
  }
}

// ---------------- fine CSR per bucket: local hist + LDS scan + scatter ----------------
template <int NBINS, int SH, typename PT>
__global__ void kb_fine(const unsigned* __restrict__ bk, const int* __restrict__ scan,
                        int* __restrict__ rp, float* __restrict__ rs,
                        PT* __restrict__ csr, int n_nodes) {
  __shared__ int hist[NBINS], cur[NBINS], lds[256];
  const int t = threadIdx.x, k = blockIdx.x;
  for (int j = t; j < NBINS; j += 256) hist[j] = 0;
  __syncthreads();
  const int s0 = scan[k * NB];
  const int e0 = (k + 1 < NBUK) ? scan[(k + 1) * NB] : N_EDGES;
  for (int i = s0 + t; i < e0; i += 256) atomicAdd(&hist[bk[i] & (NBINS - 1)], 1);
  __syncthreads();
  int v = (t < NBINS) ? hist[t] : 0;
  lds[t] = v;
  __syncthreads();
  for (int off = 1; off < 256; off <<= 1) {
    int x = (t >= off) ? lds[t - off] : 0;
    __syncthreads();
    lds[t] += x;
    __syncthreads();
  }
  if (t < NBINS) {
    int base = s0 + lds[t] - hist[t];
    cur[t] = base;
    int n = k * NBINS + t;
    if (n < n_nodes) {
      rp[n] = base;
      rs[n] = rsqrtf((float)(hist[t] > 0 ? hist[t] : 1));
    }
  }
  if (k == NBUK - 1 && t == 0) rp[n_nodes] = N_EDGES;
  __syncthreads();
  for (int i = s0 + t; i < e0; i += 256) {
    unsigned v2 = bk[i];
    int slot = atomicAdd(&cur[v2 & (NBINS - 1)], 1);
    csr[slot] = (PT)(v2 >> SH);
  }
}

// ---------------- layer-0 input prep: pad 10->16 and pre-scale by rs_read ----------------
__global__ void k_prep_h0(const float* __restrict__ h_read, const float* __restrict__ rs_r,
                          float* __restrict__ h16) {
  int i = blockIdx.x * blockDim.x + threadIdx.x;
  if (i >= N_READ * 16) return;
  int n = i >> 4, c = i & 15;
  h16[i] = (c < 10) ? h_read[n * 10 + c] * rs_r[n] : 0.0f;
}

__global__ void k_prep_W0(const float* __restrict__ W0, float* __restrict__ W0p) {
  int i = blockIdx.x * blockDim.x + threadIdx.x;
  if (i >= 16 * 64) return;
  int k = i >> 6, j = i & 63;
  W0p[i] = (k < 10) ? W0[k * 64 + j] : 0.0f;
}

// ---------------- fused aggregate + GEMM + epilogue layer ----------------
// DIN>=64 (bf16 src): block's contiguous CSR edge-id range is cooperatively staged
// into LDS (chunked at CAP for correctness at any degree). One wave = one node per
// pass; ids come from broadcast ds_read (no VMEM on the id path), 8 independent
// feature gathers in flight; per-node accumulators persist across chunks.
// DIN==16 (f32 src, L0): 8-lane sub-groups, serial edges (small layer).
// BF16DST: epilogue stores bf16 (RTNE). FC=true (L5): 128->2 projection in-block.
template <int DIN, int DOUT, bool FC, bool BF16DST, typename ET>
__launch_bounds__(256)
__global__ void k_layer(const void* __restrict__ hsrc_, const int* __restrict__ rp,
                        const ET* __restrict__ eidx, const float* __restrict__ rs_dst,
                        const float* __restrict__ W, const float* __restrict__ bias,
                        const float* __restrict__ atts, int li,
                        const float* __restrict__ rs_next,  // may be null
                        void* __restrict__ hout_,
                        const float* __restrict__ fcw, const float* __restrict__ fcb,
                        float* __restrict__ fcout, int n_dst) {
  constexpr int NT = 32;
  constexpr int RSTR = DIN + 4;  // padded LDS row stride (floats)
  constexpr int CAP = 2048;      // edge-id staging chunk (ids in LDS)
  __shared__ float rows[NT * RSTR];
  __shared__ ET ids[(DIN >= 64) ? CAP : 1];
  __shared__ int rpl[(DIN >= 64) ? (NT + 1) : 1];
  const int tid = threadIdx.x;
  const int nbase = blockIdx.x * NT;
  const int team = tid >> 6, lane = tid & 63;
  const float* hs_f = (const float*)hsrc_;
  const unsigned short* hs_b = (const unsigned short*)hsrc_;

  if constexpr (DIN >= 64) {
    // stage rp[nbase..nbase+NT] (clamped) into LDS
    if (tid <= NT) {
      int nn = nbase + tid;
      if (nn > n_dst) nn = n_dst;
      rpl[tid] = rp[nn];
    }
    __syncthreads();
    const int EB = rpl[0], EE = rpl[NT];

    // persistent per-node accumulators (8 nodes per wave)
    f2 accp[8];
    float accs[8];
#pragma unroll
    for (int t8 = 0; t8 < 8; ++t8) { accp[t8] = (f2){0.f, 0.f}; accs[t8] = 0.f; }

    for (int c0 = EB; c0 < EE; c0 += CAP) {
      const int c1 = (c0 + CAP < EE) ? c0 + CAP : EE;
      for (int i = c0 + tid; i < c1; i += 256) ids[i - c0] = eidx[i];
      __syncthreads();
#pragma unroll
      for (int t8 = 0; t8 < 8; ++t8) {
        const int t = team * 8 + t8;
        int eA = rpl[t], eB = rpl[t + 1];
        if (eA < c0) eA = c0;
        if (eB > c1) eB = c1;
        int j = eA - c0;
        const int jend = eB - c0;
        if (j < jend) {
          if constexpr (DIN == 128) {
            f2 s0 = {0.f, 0.f}, s1 = s0, s2 = s0, s3 = s0, s4 = s0, s5 = s0, s6 = s0, s7 = s0;
            for (; j + 8 <= jend; j += 8) {
              int i0 = (int)ids[j],     i1 = (int)ids[j + 1];
              int i2 = (int)ids[j + 2], i3 = (int)ids[j + 3];
              int i4 = (int)ids[j + 4], i5 = (int)ids[j + 5];
              int i6 = (int)ids[j + 6], i7 = (int)ids[j + 7];
              unsigned v0 = ((const unsigned*)(hs_b + ((size_t)i0 << 7)))[lane];
              unsigned v1 = ((const unsigned*)(hs_b + ((size_t)i1 << 7)))[lane];
              unsigned v2 = ((const unsigned*)(hs_b + ((size_t)i2 << 7)))[lane];
              unsigned v3 = ((const unsigned*)(hs_b + ((size_t)i3 << 7)))[lane];
              unsigned v4 = ((const unsigned*)(hs_b + ((size_t)i4 << 7)))[lane];
              unsigned v5 = ((const unsigned*)(hs_b + ((size_t)i5 << 7)))[lane];
              unsigned v6 = ((const unsigned*)(hs_b + ((size_t)i6 << 7)))[lane];
              unsigned v7 = ((const unsigned*)(hs_b + ((size_t)i7 << 7)))[lane];
              ga2(s0, v0); ga2(s1, v1); ga2(s2, v2); ga2(s3, v3);
              ga2(s4, v4); ga2(s5, v5); ga2(s6, v6); ga2(s7, v7);
            }
            for (; j + 4 <= jend; j += 4) {
              int i0 = (int)ids[j],     i1 = (int)ids[j + 1];
              int i2 = (int)ids[j + 2], i3 = (int)ids[j + 3];
              unsigned v0 = ((const unsigned*)(hs_b + ((size_t)i0 << 7)))[lane];
              unsigned v1 = ((const unsigned*)(hs_b + ((size_t)i1 << 7)))[lane];
              unsigned v2 = ((const unsigned*)(hs_b + ((size_t)i2 << 7)))[lane];
              unsigned v3 = ((const unsigned*)(hs_b + ((size_t)i3 << 7)))[lane];
              ga2(s0, v0); ga2(s1, v1); ga2(s2, v2); ga2(s3, v3);
            }
            for (; j < jend; ++j) {
              int i0 = (int)ids[j];
              unsigned v0 = ((const unsigned*)(hs_b + ((size_t)i0 << 7)))[lane];
              ga2(s0, v0);
            }
            accp[t8] += ((s0 + s1) + (s2 + s3)) + ((s4 + s5) + (s6 + s7));
          } else {  // DIN == 64
            float s0 = 0.f, s1 = 0.f, s2 = 0.f, s3 = 0.f, s4 = 0.f, s5 = 0.f, s6 = 0.f, s7 = 0.f;
            for (; j + 8 <= jend; j += 8) {
              int i0 = (int)ids[j],     i1 = (int)ids[j + 1];
              int i2 = (int)ids[j + 2], i3 = (int)ids[j + 3];
              int i4 = (int)ids[j + 4], i5 = (int)ids[j + 5];
              int i6 = (int)ids[j + 6], i7 = (int)ids[j + 7];
              unsigned v0 = (hs_b + ((size_t)i0 << 6))[lane];
              unsigned v1 = (hs_b + ((size_t)i1 << 6))[lane];
              unsigned v2 = (hs_b + ((size_t)i2 << 6))[lane];
              unsigned v3 = (hs_b + ((size_t)i3 << 6))[lane];
              unsigned v4 = (hs_b + ((size_t)i4 << 6))[lane];
              unsigned v5 = (hs_b + ((size_t)i5 << 6))[lane];
              unsigned v6 = (hs_b + ((size_t)i6 << 6))[lane];
              unsigned v7 = (hs_b + ((size_t)i7 << 6))[lane];
              s0 += __builtin_bit_cast(float, v0 << 16);
              s1 += __builtin_bit_cast(float, v1 << 16);
              s2 += __builtin_bit_cast(float, v2 << 16);
              s3 += __builtin_bit_cast(float, v3 << 16);
              s4 += __builtin_bit_cast(float, v4 << 16);
              s5 += __builtin_bit_cast(float, v5 << 16);
              s6 += __builtin_bit_cast(float, v6 << 16);
              s7 += __builtin_bit_cast(float, v7 << 16);
            }
            for (; j < jend; ++j) {
              int i0 = (int)ids[j];
              unsigned v0 = (hs_b + ((size_t)i0 << 6))[lane];
              s0 += __builtin_bit_cast(float, v0 << 16);
            }
            accs[t8] += ((s0 + s1) + (s2 + s3)) + ((s4 + s5) + (s6 + s7));
          }
        }
      }
      __syncthreads();  // all waves done with this id chunk before overwrite
    }

    // scale + write rows
#pragma unroll
    for (int t8 = 0; t8 < 8; ++t8) {
      const int t = team * 8 + t8;
      const int n = nbase + t;
      const float rsd = (n < n_dst) ? rs_dst[n] : 0.f;
      if constexpr (DIN == 128) {
        f2 a = accp[t8] * rsd;
        *(f2*)&rows[t * RSTR + lane * 2] = a;
      } else {
        rows[t * RSTR + lane] = accs[t8] * rsd;
      }
    }
  } else {  // DIN == 16, f32 source (L0)
    const int sub = lane >> 3, l8 = lane & 7;
    const int t = team * 8 + sub;
    const int n = nbase + t;
    f2 a0 = {0.f, 0.f}, a1 = a0, a2 = a0, a3 = a0;
    if (n < n_dst) {
      const int e0 = rp[n], e1 = rp[n + 1];
      int e = e0;
      for (; e + 4 <= e1; e += 4) {
        int s0 = (int)eidx[e], s1 = (int)eidx[e + 1];
        int s2 = (int)eidx[e + 2], s3 = (int)eidx[e + 3];
        a0 += *(const f2*)&hs_f[(size_t)s0 * 16 + l8 * 2];
        a1 += *(const f2*)&hs_f[(size_t)s1 * 16 + l8 * 2];
        a2 += *(const f2*)&hs_f[(size_t)s2 * 16 + l8 * 2];
        a3 += *(const f2*)&hs_f[(size_t)s3 * 16 + l8 * 2];
      }
      for (; e < e1; ++e) a0 += *(const f2*)&hs_f[(size_t)(int)eidx[e] * 16 + l8 * 2];
      a0 = (a0 + a1) + (a2 + a3);
      a0 *= rs_dst[n];
    }
    *(f2*)&rows[t * RSTR + l8 * 2] = a0;
  }
  __syncthreads();

  // GEMM: thread computes NPT nodes x 4 cols; nodes interleaved by NG
  constexpr int JG = DOUT / 4;
  constexpr int NG = 256 / JG;
  constexpr int NPT = NT / NG;
  const int jg = tid % JG, ng = tid / JG;
  const int j0 = jg * 4;

  f4 acc[NPT];
#pragma unroll
  for (int p = 0; p < NPT; ++p) acc[p] = (f4){0.f, 0.f, 0.f, 0.f};

#pragma unroll 2
  for (int k = 0; k < DIN; k += 4) {
    f4 w[4];
#pragma unroll
    for (int u = 0; u < 4; ++u) w[u] = *(const f4*)&W[(k + u) * DOUT + j0];
#pragma unroll
    for (int p = 0; p < NPT; ++p) {
      f4 r = *(const f4*)&rows[(ng + p * NG) * RSTR + k];
#pragma unroll
      for (int u = 0; u < 4; ++u) acc[p] += r[u] * w[u];
    }
  }

  const float gate = 1.f / (1.f + __expf(-atts[li]));
  const f4 b4 = *(const f4*)&bias[j0];

  if constexpr (!FC) {
#pragma unroll
    for (int p = 0; p < NPT; ++p) {
      const int nl = ng + p * NG;
      const int n = nbase + nl;
      if (n < n_dst) {
        f4 v = (acc[p] + b4) * gate;
#pragma unroll
        for (int c = 0; c < 4; ++c) v[c] = fmaxf(v[c], 0.f);
        if (rs_next) v *= rs_next[n];
        if constexpr (BF16DST) {
          u16x4 o = {f2bf(v[0]), f2bf(v[1]), f2bf(v[2]), f2bf(v[3])};
          *(u16x4*)&((unsigned short*)hout_)[(size_t)n * DOUT + j0] = o;
        } else {
          *(f4*)&((float*)hout_)[(size_t)n * DOUT + j0] = v;
        }
      }
    }
  } else {
    __syncthreads();  // everyone done reading rows before we overwrite it
#pragma unroll
    for (int p = 0; p < NPT; ++p) {
      const int nl = ng + p * NG;
      f4 v = (acc[p] + b4) * gate;
#pragma unroll
      for (int c = 0; c < 4; ++c) v[c] = fmaxf(v[c], 0.f);
      *(f4*)&rows[nl * RSTR + j0] = v;
    }
    __syncthreads();
    // fc: 256 threads = 32 nodes x 2 cols x 4 partial-sums
    const int nl = tid >> 3, c = (tid >> 2) & 1, part = tid & 3;
    float s = 0.f;
    const int k0 = part * 32;
#pragma unroll 8
    for (int k = k0; k < k0 + 32; ++k) s += rows[nl * RSTR + k] * fcw[k * 2 + c];
    s += __shfl_xor(s, 1);
    s += __shfl_xor(s, 2);
    const int n = nbase + nl;
    if (part == 0 && n < n_dst) fcout[n * 2 + c] = s + fcb[c];
  }
}

extern "C" void kernel_launch(void* const* d_in, const int* in_sizes, int n_in,
                              void* d_out, int out_size, void* d_ws, size_t ws_size,
                              hipStream_t stream) {
  const float* h_read = (const float*)d_in[0];
  const int* esrc = (const int*)d_in[1];
  const int* edst = (const int*)d_in[2];
  const float* W0 = (const float*)d_in[3];
  const float* b0 = (const float*)d_in[4];
  const float* W1 = (const float*)d_in[5];
  const float* b1 = (const float*)d_in[6];
  const float* W2 = (const float*)d_in[7];
  const float* b2 = (const float*)d_in[8];
  const float* W3 = (const float*)d_in[9];
  const float* b3 = (const float*)d_in[10];
  const float* W4 = (const float*)d_in[11];
  const float* b4 = (const float*)d_in[12];
  const float* W5 = (const float*)d_in[13];
  const float* b5 = (const float*)d_in[14];
  const float* atts = (const float*)d_in[15];
  const float* fcw = (const float*)d_in[16];
  const float* fcb = (const float*)d_in[17];
  float* out = (float*)d_out;

  char* w = (char*)d_ws;
  size_t off = 0;
  auto alloc = [&](size_t bytes) -> void* {
    void* p = w + off;
    off += (bytes + 15) & ~(size_t)15;  // 16B-align every array
    return p;
  };
  int* rp_r = (int*)alloc((N_READ + 1) * 4);
  int* rp_i = (int*)alloc((N_INTRON + 1) * 4);
  int* bsum = (int*)alloc(1024 * 4);
  float* rs_r = (float*)alloc(N_READ * 4);
  float* rs_i = (float*)alloc(N_INTRON * 4);
  unsigned short* csr_di_r = (unsigned short*)alloc(N_EDGES * 2);  // intron ids by read
  int* csr_si_i = (int*)alloc(N_EDGES * 4);                        // read ids by intron
  float* W0p = (float*)alloc(16 * 64 * 4);
  int* histI = (int*)alloc(NITEMS * 4);
  int* scanI = (int*)alloc((NITEMS + 1) * 4);
  int* histR = (int*)alloc(NITEMS * 4);
  int* scanR = (int*)alloc((NITEMS + 1) * 4);
  unsigned short* hR = (unsigned short*)alloc((size_t)N_READ * 128 * 2);    // bf16 features
  unsigned short* hI = (unsigned short*)alloc((size_t)N_INTRON * 128 * 2);  // bf16 features
  // Time-multiplexed aliases inside hR's 51.2 MB (dead until L1 writes it):
  //   h16 (f32, 12.8 MB) lives prep_h0 -> L0 at hR+0;
  //   bucketed edge records live kb_scatter -> kb_fine at hR+16MB (2x8 MB).
  float* h16 = (float*)hR;
  unsigned* bI = (unsigned*)((char*)hR + (size_t)16 * 1024 * 1024);
  unsigned* bR = bI + N_EDGES;

  // --- CSR build: bucket histogram -> scan -> scatter -> per-bucket fine CSR ---
  kb_hist<<<NB, 256, 0, stream>>>(esrc, edst, histI, histR);
  k_scan1<<<NITEMS / 256, 256, 0, stream>>>(histI, scanI, bsum, NITEMS);
  k_scan2<<<1, 1024, 0, stream>>>(bsum, NITEMS / 256);
  k_scan3b<<<NITEMS / 256, 256, 0, stream>>>(scanI, bsum, NITEMS);
  k_scan1<<<NITEMS / 256, 256, 0, stream>>>(histR, scanR, bsum, NITEMS);
  k_scan2<<<1, 1024, 0, stream>>>(bsum, NITEMS / 256);
  k_scan3b<<<NITEMS / 256, 256, 0, stream>>>(scanR, bsum, NITEMS);
  kb_scatter<<<NB, 256, 0, stream>>>(esrc, edst, scanI, scanR, bI, bR);
  kb_fine<64, SH_I, int><<<NBUK, 256, 0, stream>>>(bI, scanI, rp_i, rs_i, csr_si_i, N_INTRON);
  kb_fine<256, SH_R, unsigned short><<<NBUK, 256, 0, stream>>>(bR, scanR, rp_r, rs_r, csr_di_r, N_READ);

  k_prep_h0<<<(N_READ * 16 + 255) / 256, 256, 0, stream>>>(h_read, rs_r, h16);
  k_prep_W0<<<4, 256, 0, stream>>>(W0, W0p);

  // --- 6 fused layers (features stored bf16, math f32) ---
  const int gI = (N_INTRON + 31) / 32;  // 1563
  const int gR = (N_READ + 31) / 32;    // 6250
  // L0: read->intron, 16(pad)->64, src f32 h16, dst bf16 hI
  k_layer<16, 64, false, true, int><<<gI, 256, 0, stream>>>(
      h16, rp_i, csr_si_i, rs_i, W0p, b0, atts, 0, rs_i, hI, nullptr, nullptr, nullptr, N_INTRON);
  // L1: intron->read, 64->128, src bf16 hI, dst bf16 hR
  k_layer<64, 128, false, true, unsigned short><<<gR, 256, 0, stream>>>(
      hI, rp_r, csr_di_r, rs_r, W1, b1, atts, 1, rs_r, hR, nullptr, nullptr, nullptr, N_READ);
  // L2: read->intron, 128->128, src bf16 hR, dst bf16 hI
  k_layer<128, 128, false, true, int><<<gI, 256, 0, stream>>>(
      hR, rp_i, csr_si_i, rs_i, W2, b2, atts, 2, rs_i, hI, nullptr, nullptr, nullptr, N_INTRON);
  // L3: intron->read, src bf16 hI, dst bf16 hR
  k_layer<128, 128, false, true, unsigned short><<<gR, 256, 0, stream>>>(
      hI, rp_r, csr_di_r, rs_r, W3, b3, atts, 3, rs_r, hR, nullptr, nullptr, nullptr, N_READ);
  // L4: read->intron, src bf16 hR, dst bf16 hI
  k_layer<128, 128, false, true, int><<<gI, 256, 0, stream>>>(
      hR, rp_i, csr_si_i, rs_i, W4, b4, atts, 4, rs_i, hI, nullptr, nullptr, nullptr, N_INTRON);
  // L5: intron->read, src bf16 hI, fc fused in-block (f32 out)
  k_layer<128, 128, true, false, unsigned short><<<gR, 256, 0, stream>>>(
      hI, rp_r, csr_di_r, rs_r, W5, b5, atts, 5, nullptr, nullptr, fcw, fcb, out, N_READ);
}

// Round 9
// 852.066 us; speedup vs baseline: 1.0827x; 1.0827x over previous
//
#include <hip/hip_runtime.h>

#define N_READ   200000
#define N_INTRON 50000
#define N_EDGES  2000000

#define NB    256                          // edge-segment blocks for hist/scatter
#define EPB   ((N_EDGES + NB - 1) / NB)    // 7813 edges per block
#define NBUK  782                          // buckets per direction (782*64>=50000, 782*256>=200000)
#define SH_I  6                            // intron bucket shift: 64 introns/bucket
#define SH_R  8                            // read bucket shift: 256 reads/bucket
#define NITEMS (NBUK * NB)                 // 200192 (divisible by 256)

typedef float f4 __attribute__((ext_vector_type(4)));
typedef float f2 __attribute__((ext_vector_type(2)));
typedef unsigned u32x4 __attribute__((ext_vector_type(4)));
typedef unsigned short u16x4 __attribute__((ext_vector_type(4)));

// bf16 helpers: storage-only bf16; all math in f32.
static __device__ __forceinline__ unsigned short f2bf(float x) {
  unsigned u = __builtin_bit_cast(unsigned, x);
  u = (u + 0x7fffu + ((u >> 16) & 1u)) >> 16;  // RTNE
  return (unsigned short)u;
}
static __device__ __forceinline__ float blo(unsigned u) {
  return __builtin_bit_cast(float, u << 16);
}
static __device__ __forceinline__ float bhi(unsigned u) {
  return __builtin_bit_cast(float, u & 0xffff0000u);
}

// ---------------- bucket histograms (per-block LDS, no global atomics) ----------------
__global__ void kb_hist(const int* __restrict__ src, const int* __restrict__ dst,
                        int* __restrict__ histI, int* __restrict__ histR) {
  __shared__ int hI[1024], hR[1024];
  const int t = threadIdx.x, b = blockIdx.x;
  for (int k = t; k < 1024; k += 256) { hI[k] = 0; hR[k] = 0; }
  __syncthreads();
  const int s0 = b * EPB;
  const int s1 = (s0 + EPB < N_EDGES) ? s0 + EPB : N_EDGES;
  for (int i = s0 + t; i < s1; i += 256) {
    atomicAdd(&hI[dst[i] >> SH_I], 1);
    atomicAdd(&hR[src[i] >> SH_R], 1);
  }
  __syncthreads();
  for (int k = t; k < NBUK; k += 256) {
    histI[k * NB + b] = hI[k];
    histR[k * NB + b] = hR[k];
  }
}

// ---------------- exclusive scan (3 phases) ----------------
__global__ void k_scan1(const int* __restrict__ cnt, int* __restrict__ rp,
                        int* __restrict__ bsum, int n) {
  __shared__ int lds[256];
  int t = threadIdx.x;
  int i = blockIdx.x * 256 + t;
  int v = (i < n) ? cnt[i] : 0;
  lds[t] = v;
  __syncthreads();
  for (int off = 1; off < 256; off <<= 1) {
    int x = (t >= off) ? lds[t - off] : 0;
    __syncthreads();
    lds[t] += x;
    __syncthreads();
  }
  if (i < n) rp[i + 1] = lds[t];
  if (t == 255) bsum[blockIdx.x] = lds[255];
}

__global__ void k_scan2(int* __restrict__ bsum, int nb) {
  __shared__ int lds[1024];
  int t = threadIdx.x;
  int v = (t < nb) ? bsum[t] : 0;
  lds[t] = v;
  __syncthreads();
  for (int off = 1; off < 1024; off <<= 1) {
    int x = (t >= off) ? lds[t - off] : 0;
    __syncthreads();
    lds[t] += x;
    __syncthreads();
  }
  if (t < nb) bsum[t] = lds[t];
}

__global__ void k_scan3b(int* __restrict__ rp, const int* __restrict__ bsum, int n) {
  int i = blockIdx.x * 256 + threadIdx.x;
  if (i >= n) return;
  int off = (blockIdx.x == 0) ? 0 : bsum[blockIdx.x - 1];
  rp[i + 1] += off;
  if (i == 0) rp[0] = 0;
}

// ---------------- scatter edges into buckets (LDS cursors, packed u32 records) ----------------
__global__ void kb_scatter(const int* __restrict__ src, const int* __restrict__ dst,
                           const int* __restrict__ scanI, const int* __restrict__ scanR,
                           unsigned* __restrict__ bI, unsigned* __restrict__ bR) {
  __shared__ int cI[1024], cR[1024];
  const int t = threadIdx.x, b = blockIdx.x;
  for (int k = t; k < NBUK; k += 256) {
    cI[k] = scanI[k * NB + b];
    cR[k] = scanR[k * NB + b];
  }
  __syncthreads();
  const int s0 = b * EPB;
  const int s1 = (s0 + EPB < N_EDGES) ? s0 + EPB : N_EDGES;
  for (int i = s0 + t; i < s1; i += 256) {
    int s = src[i], d = dst[i];
    int slot = atomicAdd(&cI[d >> SH_I], 1);
    bI[slot] = ((unsigned)s << SH_I) | (unsigned)(d & 63);        // 18+6 = 24 bits
    int slot2 = atomicAdd(&cR[s >> SH_R], 1);
    bR[slot2] = ((unsigned)d << SH_R) | (unsigned)(s & 255);      // 16+8 = 24 bits
  }
}

// ---------------- fine CSR per bucket: local hist + LDS scan + scatter ----------------
template <int NBINS, int SH, typename PT>
__global__ void kb_fine(const unsigned* __restrict__ bk, const int* __restrict__ scan,
                        int* __restrict__ rp, float* __restrict__ rs,
                        PT* __restrict__ csr, int n_nodes) {
  __shared__ int hist[NBINS], cur[NBINS], lds[256];
  const int t = threadIdx.x, k = blockIdx.x;
  for (int j = t; j < NBINS; j += 256) hist[j] = 0;
  __syncthreads();
  const int s0 = scan[k * NB];
  const int e0 = (k + 1 < NBUK) ? scan[(k + 1) * NB] : N_EDGES;
  for (int i = s0 + t; i < e0; i += 256) atomicAdd(&hist[bk[i] & (NBINS - 1)], 1);
  __syncthreads();
  int v = (t < NBINS) ? hist[t] : 0;
  lds[t] = v;
  __syncthreads();
  for (int off = 1; off < 256; off <<= 1) {
    int x = (t >= off) ? lds[t - off] : 0;
    __syncthreads();
    lds[t] += x;
    __syncthreads();
  }
  if (t < NBINS) {
    int base = s0 + lds[t] - hist[t];
    cur[t] = base;
    int n = k * NBINS + t;
    if (n < n_nodes) {
      rp[n] = base;
      rs[n] = rsqrtf((float)(hist[t] > 0 ? hist[t] : 1));
    }
  }
  if (k == NBUK - 1 && t == 0) rp[n_nodes] = N_EDGES;
  __syncthreads();
  for (int i = s0 + t; i < e0; i += 256) {
    unsigned v2 = bk[i];
    int slot = atomicAdd(&cur[v2 & (NBINS - 1)], 1);
    csr[slot] = (PT)(v2 >> SH);
  }
}

// ---------------- layer-0 input prep: pad 10->16 and pre-scale by rs_read ----------------
__global__ void k_prep_h0(const float* __restrict__ h_read, const float* __restrict__ rs_r,
                          float* __restrict__ h16) {
  int i = blockIdx.x * blockDim.x + threadIdx.x;
  if (i >= N_READ * 16) return;
  int n = i >> 4, c = i & 15;
  h16[i] = (c < 10) ? h_read[n * 10 + c] * rs_r[n] : 0.0f;
}

__global__ void k_prep_W0(const float* __restrict__ W0, float* __restrict__ W0p) {
  int i = blockIdx.x * blockDim.x + threadIdx.x;
  if (i >= 16 * 64) return;
  int k = i >> 6, j = i & 63;
  W0p[i] = (k < 10) ? W0[k * 64 + j] : 0.0f;
}

// ---------------- fused aggregate + GEMM + epilogue layer ----------------
// Gather: slot-packed. Wave = LPS-lane groups; each group fetches one full source
// row with one dwordx4/lane instruction -> SLOTS edges per VMEM instruction
// (4 for DIN=128 bf16, 8 for DIN=64 bf16, 16 for DIN=16 f32). One wave = one node
// per pass; node edge-ids batch-loaded (1 instr/node, prefetched one node ahead),
// distributed to slots via __shfl; cross-slot reduce = log2(SLOTS) shfl_xor/node.
// BF16SRC: source rows stored bf16 (unpack to f32). BF16DST: store bf16 RTNE.
// FC=true (L5): 128->2 projection in-block.
template <int DIN, int DOUT, bool FC, bool BF16SRC, bool BF16DST, typename ET>
__launch_bounds__(256)
__global__ void k_layer(const void* __restrict__ hsrc_, const int* __restrict__ rp,
                        const ET* __restrict__ eidx, const float* __restrict__ rs_dst,
                        const float* __restrict__ W, const float* __restrict__ bias,
                        const float* __restrict__ atts, int li,
                        const float* __restrict__ rs_next,  // may be null
                        void* __restrict__ hout_,
                        const float* __restrict__ fcw, const float* __restrict__ fcb,
                        float* __restrict__ fcout, int n_dst) {
  constexpr int NT = 32;
  constexpr int RSTR = DIN + 4;  // padded LDS row stride (floats)
  __shared__ float rows[NT * RSTR];
  __shared__ int rpl[NT + 1];
  const int tid = threadIdx.x;
  const int nbase = blockIdx.x * NT;
  const int team = tid >> 6, lane = tid & 63;
  const float* hs_f = (const float*)hsrc_;
  const unsigned short* hs_b = (const unsigned short*)hsrc_;

  constexpr int LPS = (DIN * (BF16SRC ? 2 : 4)) / 16;  // lanes per source row
  constexpr int SLOTS = 64 / LPS;                       // edges per VMEM instr
  const int slot = lane / LPS, lc = lane % LPS;

  // stage rp[nbase..nbase+NT] (clamped) into LDS
  if (tid <= NT) {
    int nn = nbase + tid;
    if (nn > n_dst) nn = n_dst;
    rpl[tid] = rp[nn];
  }
  __syncthreads();

  // first id block (clamped address; garbage lanes predicated out later)
  {
    int p0 = rpl[team * 8] + lane;
    if (p0 > N_EDGES - 1) p0 = N_EDGES - 1;
    int idsC = (int)eidx[p0];

    for (int t8 = 0; t8 < 8; ++t8) {
      const int t = team * 8 + t8;
      const int e0 = rpl[t], e1 = rpl[t + 1];
      const int deg = e1 - e0;
      // prefetch next node's id block (always; index clamped)
      int pn = e1 + lane;
      if (pn > N_EDGES - 1) pn = N_EDGES - 1;
      int idsN = (int)eidx[pn];

      f4 accA = {0.f, 0.f, 0.f, 0.f};
      f4 accB = {0.f, 0.f, 0.f, 0.f};
      int processed = 0;
      while (processed < deg) {
        int m = deg - processed;
        if (m > 64) m = 64;
        if (processed > 0) {  // rare: degree > 64, serial reload
          int pr = e0 + processed + lane;
          if (pr > N_EDGES - 1) pr = N_EDGES - 1;
          idsC = (int)eidx[pr];
        }
        for (int r = 0; r < m; r += SLOTS) {
          int idv = __shfl(idsC, r + slot, 64);
          if constexpr (BF16SRC) {
            u32x4 v = *(const u32x4*)(hs_b + (size_t)idv * DIN + lc * 8);
            if (r + slot < m) {
              accA[0] += blo(v.x); accA[1] += bhi(v.x);
              accA[2] += blo(v.y); accA[3] += bhi(v.y);
              accB[0] += blo(v.z); accB[1] += bhi(v.z);
              accB[2] += blo(v.w); accB[3] += bhi(v.w);
            }
          } else {
            f4 v = *(const f4*)(hs_f + (size_t)idv * DIN + lc * 4);
            if (r + slot < m) accA += v;
          }
        }
        processed += m;
      }
      idsC = idsN;

      // cross-slot reduce
#pragma unroll
      for (int off = LPS; off < 64; off <<= 1) {
#pragma unroll
        for (int k = 0; k < 4; ++k) accA[k] += __shfl_xor(accA[k], off);
        if constexpr (BF16SRC) {
#pragma unroll
          for (int k = 0; k < 4; ++k) accB[k] += __shfl_xor(accB[k], off);
        }
      }
      if (slot == 0) {
        const int n = nbase + t;
        const float rsd = (n < n_dst) ? rs_dst[n] : 0.f;
        if constexpr (BF16SRC) {
          *(f4*)&rows[t * RSTR + lc * 8] = accA * rsd;
          *(f4*)&rows[t * RSTR + lc * 8 + 4] = accB * rsd;
        } else {
          *(f4*)&rows[t * RSTR + lc * 4] = accA * rsd;
        }
      }
    }
  }
  __syncthreads();

  // GEMM: thread computes NPT nodes x 4 cols; nodes interleaved by NG
  constexpr int JG = DOUT / 4;
  constexpr int NG = 256 / JG;
  constexpr int NPT = NT / NG;
  const int jg = tid % JG, ng = tid / JG;
  const int j0 = jg * 4;

  f4 acc[NPT];
#pragma unroll
  for (int p = 0; p < NPT; ++p) acc[p] = (f4){0.f, 0.f, 0.f, 0.f};

#pragma unroll 2
  for (int k = 0; k < DIN; k += 4) {
    f4 w[4];
#pragma unroll
    for (int u = 0; u < 4; ++u) w[u] = *(const f4*)&W[(k + u) * DOUT + j0];
#pragma unroll
    for (int p = 0; p < NPT; ++p) {
      f4 r = *(const f4*)&rows[(ng + p * NG) * RSTR + k];
#pragma unroll
      for (int u = 0; u < 4; ++u) acc[p] += r[u] * w[u];
    }
  }

  const float gate = 1.f / (1.f + __expf(-atts[li]));
  const f4 b4 = *(const f4*)&bias[j0];

  if constexpr (!FC) {
#pragma unroll
    for (int p = 0; p < NPT; ++p) {
      const int nl = ng + p * NG;
      const int n = nbase + nl;
      if (n < n_dst) {
        f4 v = (acc[p] + b4) * gate;
#pragma unroll
        for (int c = 0; c < 4; ++c) v[c] = fmaxf(v[c], 0.f);
        if (rs_next) v *= rs_next[n];
        if constexpr (BF16DST) {
          u16x4 o = {f2bf(v[0]), f2bf(v[1]), f2bf(v[2]), f2bf(v[3])};
          *(u16x4*)&((unsigned short*)hout_)[(size_t)n * DOUT + j0] = o;
        } else {
          *(f4*)&((float*)hout_)[(size_t)n * DOUT + j0] = v;
        }
      }
    }
  } else {
    __syncthreads();  // everyone done reading rows before we overwrite it
#pragma unroll
    for (int p = 0; p < NPT; ++p) {
      const int nl = ng + p * NG;
      f4 v = (acc[p] + b4) * gate;
#pragma unroll
      for (int c = 0; c < 4; ++c) v[c] = fmaxf(v[c], 0.f);
      *(f4*)&rows[nl * RSTR + j0] = v;
    }
    __syncthreads();
    // fc: 256 threads = 32 nodes x 2 cols x 4 partial-sums
    const int nl = tid >> 3, c = (tid >> 2) & 1, part = tid & 3;
    float s = 0.f;
    const int k0 = part * 32;
#pragma unroll 8
    for (int k = k0; k < k0 + 32; ++k) s += rows[nl * RSTR + k] * fcw[k * 2 + c];
    s += __shfl_xor(s, 1);
    s += __shfl_xor(s, 2);
    const int n = nbase + nl;
    if (part == 0 && n < n_dst) fcout[n * 2 + c] = s + fcb[c];
  }
}

extern "C" void kernel_launch(void* const* d_in, const int* in_sizes, int n_in,
                              void* d_out, int out_size, void* d_ws, size_t ws_size,
                              hipStream_t stream) {
  const float* h_read = (const float*)d_in[0];
  const int* esrc = (const int*)d_in[1];
  const int* edst = (const int*)d_in[2];
  const float* W0 = (const float*)d_in[3];
  const float* b0 = (const float*)d_in[4];
  const float* W1 = (const float*)d_in[5];
  const float* b1 = (const float*)d_in[6];
  const float* W2 = (const float*)d_in[7];
  const float* b2 = (const float*)d_in[8];
  const float* W3 = (const float*)d_in[9];
  const float* b3 = (const float*)d_in[10];
  const float* W4 = (const float*)d_in[11];
  const float* b4 = (const float*)d_in[12];
  const float* W5 = (const float*)d_in[13];
  const float* b5 = (const float*)d_in[14];
  const float* atts = (const float*)d_in[15];
  const float* fcw = (const float*)d_in[16];
  const float* fcb = (const float*)d_in[17];
  float* out = (float*)d_out;

  char* w = (char*)d_ws;
  size_t off = 0;
  auto alloc = [&](size_t bytes) -> void* {
    void* p = w + off;
    off += (bytes + 15) & ~(size_t)15;  // 16B-align every array
    return p;
  };
  int* rp_r = (int*)alloc((N_READ + 1) * 4);
  int* rp_i = (int*)alloc((N_INTRON + 1) * 4);
  int* bsum = (int*)alloc(1024 * 4);
  float* rs_r = (float*)alloc(N_READ * 4);
  float* rs_i = (float*)alloc(N_INTRON * 4);
  unsigned short* csr_di_r = (unsigned short*)alloc(N_EDGES * 2);  // intron ids by read
  int* csr_si_i = (int*)alloc(N_EDGES * 4);                        // read ids by intron
  float* W0p = (float*)alloc(16 * 64 * 4);
  int* histI = (int*)alloc(NITEMS * 4);
  int* scanI = (int*)alloc((NITEMS + 1) * 4);
  int* histR = (int*)alloc(NITEMS * 4);
  int* scanR = (int*)alloc((NITEMS + 1) * 4);
  unsigned short* hR = (unsigned short*)alloc((size_t)N_READ * 128 * 2);    // bf16 features
  unsigned short* hI = (unsigned short*)alloc((size_t)N_INTRON * 128 * 2);  // bf16 features
  // Time-multiplexed aliases inside hR's 51.2 MB (dead until L1 writes it):
  //   h16 (f32, 12.8 MB) lives prep_h0 -> L0 at hR+0;
  //   bucketed edge records live kb_scatter -> kb_fine at hR+16MB (2x8 MB).
  float* h16 = (float*)hR;
  unsigned* bI = (unsigned*)((char*)hR + (size_t)16 * 1024 * 1024);
  unsigned* bR = bI + N_EDGES;

  // --- CSR build: bucket histogram -> scan -> scatter -> per-bucket fine CSR ---
  kb_hist<<<NB, 256, 0, stream>>>(esrc, edst, histI, histR);
  k_scan1<<<NITEMS / 256, 256, 0, stream>>>(histI, scanI, bsum, NITEMS);
  k_scan2<<<1, 1024, 0, stream>>>(bsum, NITEMS / 256);
  k_scan3b<<<NITEMS / 256, 256, 0, stream>>>(scanI, bsum, NITEMS);
  k_scan1<<<NITEMS / 256, 256, 0, stream>>>(histR, scanR, bsum, NITEMS);
  k_scan2<<<1, 1024, 0, stream>>>(bsum, NITEMS / 256);
  k_scan3b<<<NITEMS / 256, 256, 0, stream>>>(scanR, bsum, NITEMS);
  kb_scatter<<<NB, 256, 0, stream>>>(esrc, edst, scanI, scanR, bI, bR);
  kb_fine<64, SH_I, int><<<NBUK, 256, 0, stream>>>(bI, scanI, rp_i, rs_i, csr_si_i, N_INTRON);
  kb_fine<256, SH_R, unsigned short><<<NBUK, 256, 0, stream>>>(bR, scanR, rp_r, rs_r, csr_di_r, N_READ);

  k_prep_h0<<<(N_READ * 16 + 255) / 256, 256, 0, stream>>>(h_read, rs_r, h16);
  k_prep_W0<<<4, 256, 0, stream>>>(W0, W0p);

  // --- 6 fused layers (features stored bf16, math f32) ---
  const int gI = (N_INTRON + 31) / 32;  // 1563
  const int gR = (N_READ + 31) / 32;    // 6250
  // L0: read->intron, 16(pad)->64, src f32 h16 (16 edges/instr), dst bf16 hI
  k_layer<16, 64, false, false, true, int><<<gI, 256, 0, stream>>>(
      h16, rp_i, csr_si_i, rs_i, W0p, b0, atts, 0, rs_i, hI, nullptr, nullptr, nullptr, N_INTRON);
  // L1: intron->read, 64->128, src bf16 hI (8 edges/instr), dst bf16 hR
  k_layer<64, 128, false, true, true, unsigned short><<<gR, 256, 0, stream>>>(
      hI, rp_r, csr_di_r, rs_r, W1, b1, atts, 1, rs_r, hR, nullptr, nullptr, nullptr, N_READ);
  // L2: read->intron, 128->128, src bf16 hR (4 edges/instr), dst bf16 hI
  k_layer<128, 128, false, true, true, int><<<gI, 256, 0, stream>>>(
      hR, rp_i, csr_si_i, rs_i, W2, b2, atts, 2, rs_i, hI, nullptr, nullptr, nullptr, N_INTRON);
  // L3: intron->read, src bf16 hI, dst bf16 hR
  k_layer<128, 128, false, true, true, unsigned short><<<gR, 256, 0, stream>>>(
      hI, rp_r, csr_di_r, rs_r, W3, b3, atts, 3, rs_r, hR, nullptr, nullptr, nullptr, N_READ);
  // L4: read->intron, src bf16 hR, dst bf16 hI
  k_layer<128, 128, false, true, true, int><<<gI, 256, 0, stream>>>(
      hR, rp_i, csr_si_i, rs_i, W4, b4, atts, 4, rs_i, hI, nullptr, nullptr, nullptr, N_INTRON);
  // L5: intron->read, src bf16 hI, fc fused in-block (f32 out)
  k_layer<128, 128, true, true, false, unsigned short><<<gR, 256, 0, stream>>>(
      hI, rp_r, csr_di_r, rs_r, W5, b5, atts, 5, nullptr, nullptr, fcw, fcb, out, N_READ);
}